// Round 18
// baseline (270.138 us; speedup 1.0000x reference)
//
#include <hip/hip_runtime.h>
#include <hip/hip_bf16.h>

// ---------------------------------------------------------------------------
// Quad (2x2 px/thread) LDS-staged 3x3 conv, STRIDE=1 (R11-verified).
// ---------------------------------------------------------------------------
template <int CIN1, int CIN2, int COUT, int CG, int CCH, int MINW>
__global__ __launch_bounds__(256, MINW) void convq_k(
    const float* __restrict__ in1, const float* __restrict__ in2,
    const float* __restrict__ w,    // [COUT][CIN1+CIN2][3][3]
    const float* __restrict__ bias, // [COUT]
    float* __restrict__ out,
    int Hin, int Win)
{
    constexpr int CIN = CIN1 + CIN2;
    constexpr int NG  = COUT / CG;
    constexpr int NCH = CIN / CCH;
    constexpr int P   = 34;
    constexpr int NF4 = 10;
    constexpr int WL  = NF4 * 4;
    constexpr int E4  = CCH * P * NF4;
    constexpr int NLD = (E4 + 255) / 256;
    __shared__ __align__(16) float Xs[2][CCH][P][WL];

    const int Ho = Hin, Wo = Win;
    const int tpr = Wo / 32, tpc = Ho / 32;
    int bid = blockIdx.x;
    const int tx = bid % tpr; bid /= tpr;
    const int ty = bid % tpc; bid /= tpc;
    const int g  = bid % NG;  bid /= NG;
    const int b  = bid;
    const int cbase = g * CG;

    const int tid = threadIdx.x;
    const int lx = tid & 15, ly = tid >> 4;

    const int y0 = ty * 32 - 1;
    const int xA = tx * 32 - 4;
    const int HW = Hin * Win;

    float acc[CG][4];
#pragma unroll
    for (int co = 0; co < CG; ++co) {
        float bv = bias[cbase + co];
#pragma unroll
        for (int p = 0; p < 4; ++p) acc[co][p] = bv;
    }

    int cA[NLD], lOff[NLD], em[NLD];
    bool eok[NLD], rowk[NLD], f4[NLD];
    const float* b1p[NLD];
    const float* b2p[NLD];
#pragma unroll
    for (int l = 0; l < NLD; ++l) {
        int e = tid + l * 256;
        eok[l] = (e < E4);
        int ee = eok[l] ? e : 0;
        int c  = ee / (P * NF4), r = ee % (P * NF4);
        int py = r / NF4,        jx = r % NF4;
        cA[l]   = c;
        lOff[l] = ee;
        int gy = y0 + py, c0 = xA + jx * 4;
        rowk[l] = eok[l] && ((unsigned)gy < (unsigned)Hin);
        f4[l]   = (c0 >= 0) && (c0 + 4 <= Win);
        em[l] = 0;
#pragma unroll
        for (int e2 = 0; e2 < 4; ++e2)
            if ((unsigned)(c0 + e2) < (unsigned)Win) em[l] |= 1 << e2;
        b1p[l] = (const float*)((const char*)in1 +
                 ((ptrdiff_t)(b * CIN1 + c) * HW + (ptrdiff_t)gy * Win + c0)
                 * (ptrdiff_t)sizeof(float));
        b2p[l] = (CIN2 > 0)
            ? (const float*)((const char*)in2 +
                 ((ptrdiff_t)(b * CIN2 + c - CIN1) * HW + (ptrdiff_t)gy * Win + c0)
                 * (ptrdiff_t)sizeof(float))
            : b1p[l];
    }

    float4 stg[NLD];

    auto issue = [&](int cc) {
        const size_t adv = (size_t)cc * HW;
#pragma unroll
        for (int l = 0; l < NLD; ++l) {
            float4 v = {0.0f, 0.0f, 0.0f, 0.0f};
            if (rowk[l]) {
                int ci = cc + cA[l];
                const float* p = (CIN2 == 0 || ci < CIN1) ? (b1p[l] + adv)
                                                          : (b2p[l] + adv);
                if (f4[l]) {
                    v = *(const float4*)p;
                } else {
                    float* vp = reinterpret_cast<float*>(&v);
#pragma unroll
                    for (int e2 = 0; e2 < 4; ++e2)
                        if (em[l] & (1 << e2)) vp[e2] = p[e2];
                }
            }
            stg[l] = v;
        }
    };
    auto commit = [&](int bf) {
        float4* dst = (float4*)&Xs[0][0][0][0] + (size_t)bf * (CCH * P * NF4);
#pragma unroll
        for (int l = 0; l < NLD; ++l)
            if (eok[l]) dst[lOff[l]] = stg[l];
    };

    issue(0);
    commit(0);
    __syncthreads();

    const int cb = 2 * lx + 3;

    int buf = 0;
    for (int ch = 0; ch < NCH; ++ch) {
        if (ch + 1 < NCH) issue((ch + 1) * CCH);
#pragma unroll
        for (int c = 0; c < CCH; ++c) {
#pragma unroll
            for (int ky = 0; ky < 3; ++ky) {
                const float* x0 = &Xs[buf][c][2 * ly + ky][cb];
                const float* x1 = &Xs[buf][c][2 * ly + ky + 1][cb];
                float a0 = x0[0], a1 = x0[1], a2 = x0[2], a3 = x0[3];
                float b0 = x1[0], b1v = x1[1], b2v = x1[2], b3 = x1[3];
#pragma unroll
                for (int co = 0; co < CG; ++co) {
                    const float* wp = w +
                        ((size_t)(cbase + co) * CIN + ch * CCH + c) * 9 + ky * 3;
                    float w0 = wp[0], w1 = wp[1], w2 = wp[2];
                    acc[co][0] = fmaf(a0, w0, acc[co][0]);
                    acc[co][0] = fmaf(a1, w1, acc[co][0]);
                    acc[co][0] = fmaf(a2, w2, acc[co][0]);
                    acc[co][1] = fmaf(a1, w0, acc[co][1]);
                    acc[co][1] = fmaf(a2, w1, acc[co][1]);
                    acc[co][1] = fmaf(a3, w2, acc[co][1]);
                    acc[co][2] = fmaf(b0, w0, acc[co][2]);
                    acc[co][2] = fmaf(b1v, w1, acc[co][2]);
                    acc[co][2] = fmaf(b2v, w2, acc[co][2]);
                    acc[co][3] = fmaf(b1v, w0, acc[co][3]);
                    acc[co][3] = fmaf(b2v, w1, acc[co][3]);
                    acc[co][3] = fmaf(b3, w2, acc[co][3]);
                }
            }
        }
        if (ch + 1 < NCH) {
            commit(buf ^ 1);
            __syncthreads();
            buf ^= 1;
        }
    }

    const int oy = ty * 32 + 2 * ly;
    const int ox = tx * 32 + 2 * lx;
#pragma unroll
    for (int co = 0; co < CG; ++co)
#pragma unroll
        for (int dy = 0; dy < 2; ++dy) {
            float2 v;
            v.x = fmaxf(acc[co][dy * 2 + 0], 0.0f);
            v.y = fmaxf(acc[co][dy * 2 + 1], 0.0f);
            *(float2*)&out[((size_t)(b * COUT + cbase + co) * Ho + oy + dy) * Wo + ox] = v;
        }
}

// ---------------------------------------------------------------------------
// 2-pixel LDS-staged direct 3x3 conv (R10/R11-verified, stride-2 convs).
// ---------------------------------------------------------------------------
template <int CIN1, int CIN2, int COUT, int CG, int STRIDE, int CCH, int MINW>
__global__ __launch_bounds__(256, MINW) void conv2p_k(
    const float* __restrict__ in1, const float* __restrict__ in2,
    const float* __restrict__ w,    // [COUT][CIN1+CIN2][3][3]
    const float* __restrict__ bias, // [COUT]
    float* __restrict__ out,
    int Hin, int Win)
{
    constexpr int CIN = CIN1 + CIN2;
    constexpr int NG  = COUT / CG;
    constexpr int NCH = CIN / CCH;
    constexpr int P   = 16 * STRIDE + 2;
    constexpr int NF4 = (STRIDE == 1) ? 10 : 17;
    constexpr int WL  = NF4 * 4;
    constexpr int E4  = CCH * P * NF4;
    constexpr int NLD = (E4 + 255) / 256;
    __shared__ __align__(16) float Xs[2][CCH][P][WL];

    const int Ho = Hin / STRIDE, Wo = Win / STRIDE;
    const int tpr = Wo / 32, tpc = Ho / 16;
    int bid = blockIdx.x;
    const int tx = bid % tpr; bid /= tpr;
    const int ty = bid % tpc; bid /= tpc;
    const int g  = bid % NG;  bid /= NG;
    const int b  = bid;
    const int cbase = g * CG;

    const int tid = threadIdx.x;
    const int lx = tid & 15, ly = tid >> 4;

    const int y0 = ty * 16 * STRIDE - 1;
    const int xA = tx * 32 * STRIDE - 4;
    const int HW = Hin * Win;

    float2 acc[CG];
#pragma unroll
    for (int co = 0; co < CG; ++co) {
        float bv = bias[cbase + co];
        acc[co].x = bv; acc[co].y = bv;
    }

    int cA[NLD], lOff[NLD], em[NLD];
    bool eok[NLD], rowk[NLD], f4[NLD];
    const float* b1p[NLD];
    const float* b2p[NLD];
#pragma unroll
    for (int l = 0; l < NLD; ++l) {
        int e = tid + l * 256;
        eok[l] = (e < E4);
        int ee = eok[l] ? e : 0;
        int c  = ee / (P * NF4), r = ee % (P * NF4);
        int py = r / NF4,        jx = r % NF4;
        cA[l]   = c;
        lOff[l] = ee;
        int gy = y0 + py, c0 = xA + jx * 4;
        rowk[l] = eok[l] && ((unsigned)gy < (unsigned)Hin);
        f4[l]   = (c0 >= 0) && (c0 + 4 <= Win);
        em[l] = 0;
#pragma unroll
        for (int e2 = 0; e2 < 4; ++e2)
            if ((unsigned)(c0 + e2) < (unsigned)Win) em[l] |= 1 << e2;
        b1p[l] = (const float*)((const char*)in1 +
                 ((ptrdiff_t)(b * CIN1 + c) * HW + (ptrdiff_t)gy * Win + c0)
                 * (ptrdiff_t)sizeof(float));
        b2p[l] = (CIN2 > 0)
            ? (const float*)((const char*)in2 +
                 ((ptrdiff_t)(b * CIN2 + c - CIN1) * HW + (ptrdiff_t)gy * Win + c0)
                 * (ptrdiff_t)sizeof(float))
            : b1p[l];
    }

    float4 stg[NLD];

    auto issue = [&](int cc) {
        const size_t adv = (size_t)cc * HW;
#pragma unroll
        for (int l = 0; l < NLD; ++l) {
            float4 v = {0.0f, 0.0f, 0.0f, 0.0f};
            if (rowk[l]) {
                int ci = cc + cA[l];
                const float* p = (CIN2 == 0 || ci < CIN1) ? (b1p[l] + adv)
                                                          : (b2p[l] + adv);
                if (f4[l]) {
                    v = *(const float4*)p;
                } else {
                    float* vp = reinterpret_cast<float*>(&v);
#pragma unroll
                    for (int e2 = 0; e2 < 4; ++e2)
                        if (em[l] & (1 << e2)) vp[e2] = p[e2];
                }
            }
            stg[l] = v;
        }
    };
    auto commit = [&](int bf) {
        float4* dst = (float4*)&Xs[0][0][0][0] + (size_t)bf * (CCH * P * NF4);
#pragma unroll
        for (int l = 0; l < NLD; ++l)
            if (eok[l]) dst[lOff[l]] = stg[l];
    };

    issue(0);
    commit(0);
    __syncthreads();

    const int cb = (2 * lx) * STRIDE + 3;

    int buf = 0;
    for (int ch = 0; ch < NCH; ++ch) {
        if (ch + 1 < NCH) issue((ch + 1) * CCH);
#pragma unroll
        for (int c = 0; c < CCH; ++c) {
#pragma unroll
            for (int ky = 0; ky < 3; ++ky) {
                const float* xr = &Xs[buf][c][ly * STRIDE + ky][0];
                float2 r0, r1, r2;
                r0.x = xr[cb + 0]; r0.y = xr[cb + 0 + STRIDE];
                r1.x = xr[cb + 1]; r1.y = xr[cb + 1 + STRIDE];
                r2.x = xr[cb + 2]; r2.y = xr[cb + 2 + STRIDE];
#pragma unroll
                for (int co = 0; co < CG; ++co) {
                    const float* wp = w +
                        ((size_t)(cbase + co) * CIN + ch * CCH + c) * 9 + ky * 3;
                    float w0 = wp[0], w1 = wp[1], w2 = wp[2];
                    float2 a = acc[co];
                    a.x = fmaf(r0.x, w0, a.x); a.y = fmaf(r0.y, w0, a.y);
                    a.x = fmaf(r1.x, w1, a.x); a.y = fmaf(r1.y, w1, a.y);
                    a.x = fmaf(r2.x, w2, a.x); a.y = fmaf(r2.y, w2, a.y);
                    acc[co] = a;
                }
            }
        }
        if (ch + 1 < NCH) {
            commit(buf ^ 1);
            __syncthreads();
            buf ^= 1;
        }
    }

    const int oy = ty * 16 + ly;
    const int ox = tx * 32 + 2 * lx;
#pragma unroll
    for (int co = 0; co < CG; ++co) {
        float2 v;
        v.x = fmaxf(acc[co].x, 0.0f);
        v.y = fmaxf(acc[co].y, 0.0f);
        *(float2*)&out[((size_t)(b * COUT + cbase + co) * Ho + oy) * Wo + ox] = v;
    }
}

// ---------------------------------------------------------------------------
// FC1 stage: split-K 64x384 (was 32x768 — 512 blocks = 2 blocks/CU was
// latency-bound at Occupancy 18%; 1024 blocks doubles the wave pool).
// float4 B-load (R15-verified). part = [64][32][1024].
// ---------------------------------------------------------------------------
#define FC1_K 24576
#define FC1_N 1024
#define FC1_M 32
#define FC1_KS 64   // k splits
#define FC1_KC 384  // k per split
#define FC1_KP 64   // k per phase
#define FC1_NT 64   // n per block

__global__ __launch_bounds__(256) void fc1_stage_k(
    const float* __restrict__ xs,   // [32][24576]
    const float* __restrict__ fw1,  // [1024][24576]
    float* __restrict__ part)       // [KS][32][1024]
{
    __shared__ __align__(16) float As[FC1_KP][36];
    __shared__ __align__(16) float Bs[FC1_KP][66];

    const int tid = threadIdx.x;
    const int n0 = blockIdx.x * FC1_NT;
    const int ks = blockIdx.y;
    const int k0 = ks * FC1_KC;
    const int lane = tid & 63;
    const int grp = tid >> 6;

    const int m4 = (tid & 7) * 4;
    const int n2 = (tid >> 3) * 2;

    const int bk4 = (tid & 15) * 4;
    const int bnl = tid >> 4;

    float acc[4][2];
#pragma unroll
    for (int i = 0; i < 4; ++i)
#pragma unroll
        for (int j = 0; j < 2; ++j) acc[i][j] = 0.0f;

    for (int p = 0; p < FC1_KC / FC1_KP; ++p) {
        const int kc = k0 + p * FC1_KP;
#pragma unroll
        for (int r = 0; r < 8; ++r) {
            int m = grp * 8 + r;
            As[lane][m] = xs[(size_t)m * FC1_K + kc + lane];
        }
#pragma unroll
        for (int r = 0; r < 4; ++r) {
            int nl = r * 16 + bnl;
            float4 v = *(const float4*)&fw1[(size_t)(n0 + nl) * FC1_K + kc + bk4];
            Bs[bk4 + 0][nl] = v.x;
            Bs[bk4 + 1][nl] = v.y;
            Bs[bk4 + 2][nl] = v.z;
            Bs[bk4 + 3][nl] = v.w;
        }
        __syncthreads();
#pragma unroll 8
        for (int k = 0; k < FC1_KP; ++k) {
            float4 a = *(const float4*)&As[k][m4];
            float2 bv = *(const float2*)&Bs[k][n2];
            acc[0][0] += a.x * bv.x; acc[0][1] += a.x * bv.y;
            acc[1][0] += a.y * bv.x; acc[1][1] += a.y * bv.y;
            acc[2][0] += a.z * bv.x; acc[2][1] += a.z * bv.y;
            acc[3][0] += a.w * bv.x; acc[3][1] += a.w * bv.y;
        }
        __syncthreads();
    }
#pragma unroll
    for (int i = 0; i < 4; ++i)
#pragma unroll
        for (int j = 0; j < 2; ++j)
            part[((size_t)ks * FC1_M + (m4 + i)) * FC1_N + n0 + n2 + j] = acc[i][j];
}

// ---------------------------------------------------------------------------
// Fused FC tail (R15-verified math; reduce loop now over 64 splits).
// ---------------------------------------------------------------------------
__global__ __launch_bounds__(256) void fc_tail_k(
    const float* __restrict__ part, const float* __restrict__ fb1,
    const float* __restrict__ fw2,  const float* __restrict__ fb2,
    const float* __restrict__ fw3,  const float* __restrict__ fb3,
    float* __restrict__ theta_out)
{
    __shared__ float hs[1024];
    __shared__ float h2s[32];
    const int m = blockIdx.x;
    const int tid = threadIdx.x;

    for (int n = tid; n < FC1_N; n += 256) {
        float s = fb1[n];
#pragma unroll 8
        for (int ks = 0; ks < FC1_KS; ++ks)
            s += part[((size_t)ks * FC1_M + m) * FC1_N + n];
        hs[n] = fmaxf(s, 0.0f);
    }
    __syncthreads();

    const int wave = tid >> 6, lane = tid & 63;
#pragma unroll 1
    for (int nn = 0; nn < 8; ++nn) {
        int n = wave * 8 + nn;
        float p = 0.0f;
        for (int k = lane; k < 1024; k += 64)
            p += fw2[n * 1024 + k] * hs[k];
#pragma unroll
        for (int off = 32; off; off >>= 1) p += __shfl_xor(p, off);
        if (lane == 0) h2s[n] = fmaxf(p + fb2[n], 0.0f);
    }
    __syncthreads();

    if (tid < 4) {
        int j = tid;
        float s = fb3[j];
#pragma unroll
        for (int k = 0; k < 32; ++k) s += h2s[k] * fw3[j * 32 + k];
        float* th = theta_out + m * 6;
        if (j == 0)      { th[0] = 1.0f / (1.0f + expf(-s)); th[1] = 0.0f; }
        else if (j == 1) { th[4] = 1.0f / (1.0f + expf(-s)); th[3] = 0.0f; }
        else if (j == 2) { th[2] = tanhf(s); }
        else             { th[5] = tanhf(s); }
    }
}

// ---------------------------------------------------------------------------
// Bilinear grid-sample, padding_mode='zeros', align_corners=False. C=1.
// ---------------------------------------------------------------------------
__global__ __launch_bounds__(256) void sampler_k(
    const float* __restrict__ im, const float* __restrict__ theta,
    float* __restrict__ out)
{
    int idx = blockIdx.x * 256 + threadIdx.x;
    int x = idx & 255;
    int y = (idx >> 8) & 255;
    int b = idx >> 16;
    const float* th = theta + b * 6;
    float xsn = (2.0f * x + 1.0f) * (1.0f / 256.0f) - 1.0f;
    float ysn = (2.0f * y + 1.0f) * (1.0f / 256.0f) - 1.0f;
    float gx = th[0] * xsn + th[1] * ysn + th[2];
    float gy = th[3] * xsn + th[4] * ysn + th[5];
    float ix = ((gx + 1.0f) * 256.0f - 1.0f) * 0.5f;
    float iy = ((gy + 1.0f) * 256.0f - 1.0f) * 0.5f;
    float x0 = floorf(ix), y0 = floorf(iy);
    float wx1 = ix - x0, wy1 = iy - y0;
    float wx0 = 1.0f - wx1, wy0 = 1.0f - wy1;
    const float* src = im + (size_t)b * 65536;

    auto g = [&](float xf, float yf) -> float {
        if (xf < 0.0f || xf > 255.0f || yf < 0.0f || yf > 255.0f) return 0.0f;
        int xi = (int)xf, yi = (int)yf;
        return src[yi * 256 + xi];
    };
    float v00 = g(x0, y0);
    float v10 = g(x0 + 1.0f, y0);
    float v01 = g(x0, y0 + 1.0f);
    float v11 = g(x0 + 1.0f, y0 + 1.0f);
    out[idx] = v00 * wx0 * wy0 + v10 * wx1 * wy0 + v01 * wx0 * wy1 + v11 * wx1 * wy1;
}

// ---------------------------------------------------------------------------
// Workspace layouts (floats):
// CHUNKED (ws < 84MB): x2@0, x1c@4194304, x3@4194304, x4@12582912,
//   x5@4194304, x6@14680064, part@0 (2,097,152 floats, x2 dead). Peak 61.9MB.
// BIG (ws >= 84MB): x2@0, x1@4194304 (ends 20971520), x3@4194304,
//   x4@12582912, x5@14680064, x6@17825792, part@0.
// Grid formula everywhere: B * NG * tpc * tpr (audited per launch).
// ---------------------------------------------------------------------------
extern "C" void kernel_launch(void* const* d_in, const int* in_sizes, int n_in,
                              void* d_out, int out_size, void* d_ws, size_t ws_size,
                              hipStream_t stream)
{
    const float* im  = (const float*)d_in[0];
    const float* w1  = (const float*)d_in[1];  const float* b1 = (const float*)d_in[2];
    const float* w2  = (const float*)d_in[3];  const float* b2 = (const float*)d_in[4];
    const float* w3  = (const float*)d_in[5];  const float* b3 = (const float*)d_in[6];
    const float* w4  = (const float*)d_in[7];  const float* b4 = (const float*)d_in[8];
    const float* w5  = (const float*)d_in[9];  const float* b5 = (const float*)d_in[10];
    const float* w6  = (const float*)d_in[11]; const float* b6 = (const float*)d_in[12];
    const float* fw1 = (const float*)d_in[13]; const float* fb1 = (const float*)d_in[14];
    const float* fw2 = (const float*)d_in[15]; const float* fb2 = (const float*)d_in[16];
    const float* fw3 = (const float*)d_in[17]; const float* fb3 = (const float*)d_in[18];

    float* out = (float*)d_out;
    float* ws  = (float*)d_ws;

    float* theta = out + 32 * 65536;

    const bool big = ws_size >= (size_t)20971520 * 4;  // 83.9 MB

    float* x2   = ws + 0;
    float* part = ws + 0;

    if (big) {
        float* x1 = ws + 4194304;   // 32x8x256x256
        float* x3 = ws + 4194304;
        float* x4 = ws + 12582912;
        float* x5 = ws + 14680064;
        float* x6 = ws + 17825792;

        // conv1: B32 NG1 tpc8 tpr8 = 2048
        convq_k<1, 0, 8, 8, 1, 4><<<2048, 256, 0, stream>>>(
            im, nullptr, w1, b1, x1, 256, 256);
        // conv2: B32 NG1 tpc8 tpr4 = 1024
        conv2p_k<8, 1, 8, 8, 2, 1, 6><<<1024, 256, 0, stream>>>(
            x1, im, w2, b2, x2, 256, 256);
        // conv3: B32 NG2 tpc4 tpr4 = 1024
        convq_k<8, 0, 16, 8, 2, 4><<<1024, 256, 0, stream>>>(
            x2, nullptr, w3, b3, x3, 128, 128);
        // conv4: B32 NG2 tpc4 tpr2 = 512
        conv2p_k<16, 8, 16, 8, 2, 1, 6><<<512, 256, 0, stream>>>(
            x3, x2, w4, b4, x4, 128, 128);
        // conv5: B32 NG4 tpc2 tpr2 = 512
        convq_k<16, 0, 24, 6, 2, 4><<<512, 256, 0, stream>>>(
            x4, nullptr, w5, b5, x5, 64, 64);
        // conv6: B32 NG6 tpc2 tpr1 = 384
        conv2p_k<24, 16, 24, 4, 2, 1, 6><<<384, 256, 0, stream>>>(
            x5, x4, w6, b6, x6, 64, 64);

        fc1_stage_k<<<dim3(16, FC1_KS), 256, 0, stream>>>(x6, fw1, part);
        fc_tail_k<<<32, 256, 0, stream>>>(part, fb1, fw2, fb2, fw3, fb3, theta);
    } else {
        float* x1c = ws + 4194304;  // 16-batch chunk
        float* x3  = ws + 4194304;
        float* x4  = ws + 12582912;
        float* x5  = ws + 4194304;
        float* x6  = ws + 14680064;

        for (int c = 0; c < 2; ++c) {
            const float* imc = im + (size_t)c * 16 * 65536;
            // conv1 chunk: B16 NG1 tpc8 tpr8 = 1024
            convq_k<1, 0, 8, 8, 1, 4><<<1024, 256, 0, stream>>>(
                imc, nullptr, w1, b1, x1c, 256, 256);
            // conv2 chunk: B16 NG1 tpc8 tpr4 = 512
            conv2p_k<8, 1, 8, 8, 2, 1, 6><<<512, 256, 0, stream>>>(
                x1c, imc, w2, b2, x2 + (size_t)c * 2097152, 256, 256);
        }
        // conv3: B32 NG2 tpc4 tpr4 = 1024
        convq_k<8, 0, 16, 8, 2, 4><<<1024, 256, 0, stream>>>(
            x2, nullptr, w3, b3, x3, 128, 128);
        // conv4: B32 NG2 tpc4 tpr2 = 512
        conv2p_k<16, 8, 16, 8, 2, 1, 6><<<512, 256, 0, stream>>>(
            x3, x2, w4, b4, x4, 128, 128);
        // conv5: B32 NG4 tpc2 tpr2 = 512
        convq_k<16, 0, 24, 6, 2, 4><<<512, 256, 0, stream>>>(
            x4, nullptr, w5, b5, x5, 64, 64);
        // conv6: B32 NG6 tpc2 tpr1 = 384
        conv2p_k<24, 16, 24, 4, 2, 1, 6><<<384, 256, 0, stream>>>(
            x5, x4, w6, b6, x6, 64, 64);

        fc1_stage_k<<<dim3(16, FC1_KS), 256, 0, stream>>>(x6, fw1, part);
        fc_tail_k<<<32, 256, 0, stream>>>(part, fb1, fw2, fb2, fw3, fb3, theta);
    }

    // grid sample from theta (written into d_out tail, stream-ordered)
    sampler_k<<<8192, 256, 0, stream>>>(im, theta, out);
}

// Round 19
// 264.305 us; speedup vs baseline: 1.0221x; 1.0221x over previous
//
#include <hip/hip_runtime.h>
#include <hip/hip_bf16.h>

// ---------------------------------------------------------------------------
// Quad (2x2 px/thread) LDS-staged 3x3 conv, STRIDE=1 (R11-verified).
// ---------------------------------------------------------------------------
template <int CIN1, int CIN2, int COUT, int CG, int CCH, int MINW>
__global__ __launch_bounds__(256, MINW) void convq_k(
    const float* __restrict__ in1, const float* __restrict__ in2,
    const float* __restrict__ w,    // [COUT][CIN1+CIN2][3][3]
    const float* __restrict__ bias, // [COUT]
    float* __restrict__ out,
    int Hin, int Win)
{
    constexpr int CIN = CIN1 + CIN2;
    constexpr int NG  = COUT / CG;
    constexpr int NCH = CIN / CCH;
    constexpr int P   = 34;
    constexpr int NF4 = 10;
    constexpr int WL  = NF4 * 4;
    constexpr int E4  = CCH * P * NF4;
    constexpr int NLD = (E4 + 255) / 256;
    __shared__ __align__(16) float Xs[2][CCH][P][WL];

    const int Ho = Hin, Wo = Win;
    const int tpr = Wo / 32, tpc = Ho / 32;
    int bid = blockIdx.x;
    const int tx = bid % tpr; bid /= tpr;
    const int ty = bid % tpc; bid /= tpc;
    const int g  = bid % NG;  bid /= NG;
    const int b  = bid;
    const int cbase = g * CG;

    const int tid = threadIdx.x;
    const int lx = tid & 15, ly = tid >> 4;

    const int y0 = ty * 32 - 1;
    const int xA = tx * 32 - 4;
    const int HW = Hin * Win;

    float acc[CG][4];
#pragma unroll
    for (int co = 0; co < CG; ++co) {
        float bv = bias[cbase + co];
#pragma unroll
        for (int p = 0; p < 4; ++p) acc[co][p] = bv;
    }

    int cA[NLD], lOff[NLD], em[NLD];
    bool eok[NLD], rowk[NLD], f4[NLD];
    const float* b1p[NLD];
    const float* b2p[NLD];
#pragma unroll
    for (int l = 0; l < NLD; ++l) {
        int e = tid + l * 256;
        eok[l] = (e < E4);
        int ee = eok[l] ? e : 0;
        int c  = ee / (P * NF4), r = ee % (P * NF4);
        int py = r / NF4,        jx = r % NF4;
        cA[l]   = c;
        lOff[l] = ee;
        int gy = y0 + py, c0 = xA + jx * 4;
        rowk[l] = eok[l] && ((unsigned)gy < (unsigned)Hin);
        f4[l]   = (c0 >= 0) && (c0 + 4 <= Win);
        em[l] = 0;
#pragma unroll
        for (int e2 = 0; e2 < 4; ++e2)
            if ((unsigned)(c0 + e2) < (unsigned)Win) em[l] |= 1 << e2;
        b1p[l] = (const float*)((const char*)in1 +
                 ((ptrdiff_t)(b * CIN1 + c) * HW + (ptrdiff_t)gy * Win + c0)
                 * (ptrdiff_t)sizeof(float));
        b2p[l] = (CIN2 > 0)
            ? (const float*)((const char*)in2 +
                 ((ptrdiff_t)(b * CIN2 + c - CIN1) * HW + (ptrdiff_t)gy * Win + c0)
                 * (ptrdiff_t)sizeof(float))
            : b1p[l];
    }

    float4 stg[NLD];

    auto issue = [&](int cc) {
        const size_t adv = (size_t)cc * HW;
#pragma unroll
        for (int l = 0; l < NLD; ++l) {
            float4 v = {0.0f, 0.0f, 0.0f, 0.0f};
            if (rowk[l]) {
                int ci = cc + cA[l];
                const float* p = (CIN2 == 0 || ci < CIN1) ? (b1p[l] + adv)
                                                          : (b2p[l] + adv);
                if (f4[l]) {
                    v = *(const float4*)p;
                } else {
                    float* vp = reinterpret_cast<float*>(&v);
#pragma unroll
                    for (int e2 = 0; e2 < 4; ++e2)
                        if (em[l] & (1 << e2)) vp[e2] = p[e2];
                }
            }
            stg[l] = v;
        }
    };
    auto commit = [&](int bf) {
        float4* dst = (float4*)&Xs[0][0][0][0] + (size_t)bf * (CCH * P * NF4);
#pragma unroll
        for (int l = 0; l < NLD; ++l)
            if (eok[l]) dst[lOff[l]] = stg[l];
    };

    issue(0);
    commit(0);
    __syncthreads();

    const int cb = 2 * lx + 3;

    int buf = 0;
    for (int ch = 0; ch < NCH; ++ch) {
        if (ch + 1 < NCH) issue((ch + 1) * CCH);
#pragma unroll
        for (int c = 0; c < CCH; ++c) {
#pragma unroll
            for (int ky = 0; ky < 3; ++ky) {
                const float* x0 = &Xs[buf][c][2 * ly + ky][cb];
                const float* x1 = &Xs[buf][c][2 * ly + ky + 1][cb];
                float a0 = x0[0], a1 = x0[1], a2 = x0[2], a3 = x0[3];
                float b0 = x1[0], b1v = x1[1], b2v = x1[2], b3 = x1[3];
#pragma unroll
                for (int co = 0; co < CG; ++co) {
                    const float* wp = w +
                        ((size_t)(cbase + co) * CIN + ch * CCH + c) * 9 + ky * 3;
                    float w0 = wp[0], w1 = wp[1], w2 = wp[2];
                    acc[co][0] = fmaf(a0, w0, acc[co][0]);
                    acc[co][0] = fmaf(a1, w1, acc[co][0]);
                    acc[co][0] = fmaf(a2, w2, acc[co][0]);
                    acc[co][1] = fmaf(a1, w0, acc[co][1]);
                    acc[co][1] = fmaf(a2, w1, acc[co][1]);
                    acc[co][1] = fmaf(a3, w2, acc[co][1]);
                    acc[co][2] = fmaf(b0, w0, acc[co][2]);
                    acc[co][2] = fmaf(b1v, w1, acc[co][2]);
                    acc[co][2] = fmaf(b2v, w2, acc[co][2]);
                    acc[co][3] = fmaf(b1v, w0, acc[co][3]);
                    acc[co][3] = fmaf(b2v, w1, acc[co][3]);
                    acc[co][3] = fmaf(b3, w2, acc[co][3]);
                }
            }
        }
        if (ch + 1 < NCH) {
            commit(buf ^ 1);
            __syncthreads();
            buf ^= 1;
        }
    }

    const int oy = ty * 32 + 2 * ly;
    const int ox = tx * 32 + 2 * lx;
#pragma unroll
    for (int co = 0; co < CG; ++co)
#pragma unroll
        for (int dy = 0; dy < 2; ++dy) {
            float2 v;
            v.x = fmaxf(acc[co][dy * 2 + 0], 0.0f);
            v.y = fmaxf(acc[co][dy * 2 + 1], 0.0f);
            *(float2*)&out[((size_t)(b * COUT + cbase + co) * Ho + oy + dy) * Wo + ox] = v;
        }
}

// ---------------------------------------------------------------------------
// 2-pixel LDS-staged direct 3x3 conv (R10/R11-verified, stride-2 convs).
// ---------------------------------------------------------------------------
template <int CIN1, int CIN2, int COUT, int CG, int STRIDE, int CCH, int MINW>
__global__ __launch_bounds__(256, MINW) void conv2p_k(
    const float* __restrict__ in1, const float* __restrict__ in2,
    const float* __restrict__ w,    // [COUT][CIN1+CIN2][3][3]
    const float* __restrict__ bias, // [COUT]
    float* __restrict__ out,
    int Hin, int Win)
{
    constexpr int CIN = CIN1 + CIN2;
    constexpr int NG  = COUT / CG;
    constexpr int NCH = CIN / CCH;
    constexpr int P   = 16 * STRIDE + 2;
    constexpr int NF4 = (STRIDE == 1) ? 10 : 17;
    constexpr int WL  = NF4 * 4;
    constexpr int E4  = CCH * P * NF4;
    constexpr int NLD = (E4 + 255) / 256;
    __shared__ __align__(16) float Xs[2][CCH][P][WL];

    const int Ho = Hin / STRIDE, Wo = Win / STRIDE;
    const int tpr = Wo / 32, tpc = Ho / 16;
    int bid = blockIdx.x;
    const int tx = bid % tpr; bid /= tpr;
    const int ty = bid % tpc; bid /= tpc;
    const int g  = bid % NG;  bid /= NG;
    const int b  = bid;
    const int cbase = g * CG;

    const int tid = threadIdx.x;
    const int lx = tid & 15, ly = tid >> 4;

    const int y0 = ty * 16 * STRIDE - 1;
    const int xA = tx * 32 * STRIDE - 4;
    const int HW = Hin * Win;

    float2 acc[CG];
#pragma unroll
    for (int co = 0; co < CG; ++co) {
        float bv = bias[cbase + co];
        acc[co].x = bv; acc[co].y = bv;
    }

    int cA[NLD], lOff[NLD], em[NLD];
    bool eok[NLD], rowk[NLD], f4[NLD];
    const float* b1p[NLD];
    const float* b2p[NLD];
#pragma unroll
    for (int l = 0; l < NLD; ++l) {
        int e = tid + l * 256;
        eok[l] = (e < E4);
        int ee = eok[l] ? e : 0;
        int c  = ee / (P * NF4), r = ee % (P * NF4);
        int py = r / NF4,        jx = r % NF4;
        cA[l]   = c;
        lOff[l] = ee;
        int gy = y0 + py, c0 = xA + jx * 4;
        rowk[l] = eok[l] && ((unsigned)gy < (unsigned)Hin);
        f4[l]   = (c0 >= 0) && (c0 + 4 <= Win);
        em[l] = 0;
#pragma unroll
        for (int e2 = 0; e2 < 4; ++e2)
            if ((unsigned)(c0 + e2) < (unsigned)Win) em[l] |= 1 << e2;
        b1p[l] = (const float*)((const char*)in1 +
                 ((ptrdiff_t)(b * CIN1 + c) * HW + (ptrdiff_t)gy * Win + c0)
                 * (ptrdiff_t)sizeof(float));
        b2p[l] = (CIN2 > 0)
            ? (const float*)((const char*)in2 +
                 ((ptrdiff_t)(b * CIN2 + c - CIN1) * HW + (ptrdiff_t)gy * Win + c0)
                 * (ptrdiff_t)sizeof(float))
            : b1p[l];
    }

    float4 stg[NLD];

    auto issue = [&](int cc) {
        const size_t adv = (size_t)cc * HW;
#pragma unroll
        for (int l = 0; l < NLD; ++l) {
            float4 v = {0.0f, 0.0f, 0.0f, 0.0f};
            if (rowk[l]) {
                int ci = cc + cA[l];
                const float* p = (CIN2 == 0 || ci < CIN1) ? (b1p[l] + adv)
                                                          : (b2p[l] + adv);
                if (f4[l]) {
                    v = *(const float4*)p;
                } else {
                    float* vp = reinterpret_cast<float*>(&v);
#pragma unroll
                    for (int e2 = 0; e2 < 4; ++e2)
                        if (em[l] & (1 << e2)) vp[e2] = p[e2];
                }
            }
            stg[l] = v;
        }
    };
    auto commit = [&](int bf) {
        float4* dst = (float4*)&Xs[0][0][0][0] + (size_t)bf * (CCH * P * NF4);
#pragma unroll
        for (int l = 0; l < NLD; ++l)
            if (eok[l]) dst[lOff[l]] = stg[l];
    };

    issue(0);
    commit(0);
    __syncthreads();

    const int cb = (2 * lx) * STRIDE + 3;

    int buf = 0;
    for (int ch = 0; ch < NCH; ++ch) {
        if (ch + 1 < NCH) issue((ch + 1) * CCH);
#pragma unroll
        for (int c = 0; c < CCH; ++c) {
#pragma unroll
            for (int ky = 0; ky < 3; ++ky) {
                const float* xr = &Xs[buf][c][ly * STRIDE + ky][0];
                float2 r0, r1, r2;
                r0.x = xr[cb + 0]; r0.y = xr[cb + 0 + STRIDE];
                r1.x = xr[cb + 1]; r1.y = xr[cb + 1 + STRIDE];
                r2.x = xr[cb + 2]; r2.y = xr[cb + 2 + STRIDE];
#pragma unroll
                for (int co = 0; co < CG; ++co) {
                    const float* wp = w +
                        ((size_t)(cbase + co) * CIN + ch * CCH + c) * 9 + ky * 3;
                    float w0 = wp[0], w1 = wp[1], w2 = wp[2];
                    float2 a = acc[co];
                    a.x = fmaf(r0.x, w0, a.x); a.y = fmaf(r0.y, w0, a.y);
                    a.x = fmaf(r1.x, w1, a.x); a.y = fmaf(r1.y, w1, a.y);
                    a.x = fmaf(r2.x, w2, a.x); a.y = fmaf(r2.y, w2, a.y);
                    acc[co] = a;
                }
            }
        }
        if (ch + 1 < NCH) {
            commit(buf ^ 1);
            __syncthreads();
            buf ^= 1;
        }
    }

    const int oy = ty * 16 + ly;
    const int ox = tx * 32 + 2 * lx;
#pragma unroll
    for (int co = 0; co < CG; ++co) {
        float2 v;
        v.x = fmaxf(acc[co].x, 0.0f);
        v.y = fmaxf(acc[co].y, 0.0f);
        *(float2*)&out[((size_t)(b * COUT + cbase + co) * Ho + oy) * Wo + ox] = v;
    }
}

// ---------------------------------------------------------------------------
// FC1 stage: split-K 64x384, 1024 blocks (R18), float4 B-load (R15-verified).
// ---------------------------------------------------------------------------
#define FC1_K 24576
#define FC1_N 1024
#define FC1_M 32
#define FC1_KS 64   // k splits
#define FC1_KC 384  // k per split
#define FC1_KP 64   // k per phase
#define FC1_NT 64   // n per block

__global__ __launch_bounds__(256) void fc1_stage_k(
    const float* __restrict__ xs,   // [32][24576]
    const float* __restrict__ fw1,  // [1024][24576]
    float* __restrict__ part)       // [KS][32][1024]
{
    __shared__ __align__(16) float As[FC1_KP][36];
    __shared__ __align__(16) float Bs[FC1_KP][66];

    const int tid = threadIdx.x;
    const int n0 = blockIdx.x * FC1_NT;
    const int ks = blockIdx.y;
    const int k0 = ks * FC1_KC;
    const int lane = tid & 63;
    const int grp = tid >> 6;

    const int m4 = (tid & 7) * 4;
    const int n2 = (tid >> 3) * 2;

    const int bk4 = (tid & 15) * 4;
    const int bnl = tid >> 4;

    float acc[4][2];
#pragma unroll
    for (int i = 0; i < 4; ++i)
#pragma unroll
        for (int j = 0; j < 2; ++j) acc[i][j] = 0.0f;

    for (int p = 0; p < FC1_KC / FC1_KP; ++p) {
        const int kc = k0 + p * FC1_KP;
#pragma unroll
        for (int r = 0; r < 8; ++r) {
            int m = grp * 8 + r;
            As[lane][m] = xs[(size_t)m * FC1_K + kc + lane];
        }
#pragma unroll
        for (int r = 0; r < 4; ++r) {
            int nl = r * 16 + bnl;
            float4 v = *(const float4*)&fw1[(size_t)(n0 + nl) * FC1_K + kc + bk4];
            Bs[bk4 + 0][nl] = v.x;
            Bs[bk4 + 1][nl] = v.y;
            Bs[bk4 + 2][nl] = v.z;
            Bs[bk4 + 3][nl] = v.w;
        }
        __syncthreads();
#pragma unroll 8
        for (int k = 0; k < FC1_KP; ++k) {
            float4 a = *(const float4*)&As[k][m4];
            float2 bv = *(const float2*)&Bs[k][n2];
            acc[0][0] += a.x * bv.x; acc[0][1] += a.x * bv.y;
            acc[1][0] += a.y * bv.x; acc[1][1] += a.y * bv.y;
            acc[2][0] += a.z * bv.x; acc[2][1] += a.z * bv.y;
            acc[3][0] += a.w * bv.x; acc[3][1] += a.w * bv.y;
        }
        __syncthreads();
    }
#pragma unroll
    for (int i = 0; i < 4; ++i)
#pragma unroll
        for (int j = 0; j < 2; ++j)
            part[((size_t)ks * FC1_M + (m4 + i)) * FC1_N + n0 + n2 + j] = acc[i][j];
}

// ---------------------------------------------------------------------------
// FC1 reduce: h1[32][1024] = relu(sum_ks part + fb1). 128 blocks (R13-verified
// structure) — 512 waves vs the 32-block fused tail that ran at 58us/1.3% occ.
// ---------------------------------------------------------------------------
__global__ __launch_bounds__(256) void fc1_reduce_k(
    const float* __restrict__ part, const float* __restrict__ fb1,
    float* __restrict__ h1)
{
    int idx = blockIdx.x * 256 + threadIdx.x; // 32768
    int n = idx & (FC1_N - 1);
    int m = idx >> 10;
    float s = fb1[n];
#pragma unroll 8
    for (int ks = 0; ks < FC1_KS; ++ks)
        s += part[((size_t)ks * FC1_M + m) * FC1_N + n];
    h1[idx] = fmaxf(s, 0.0f);
}

// ---------------------------------------------------------------------------
// FC tail2: fc2 + fc3 + theta, one block per batch m (R13 fc2_k structure).
// ---------------------------------------------------------------------------
__global__ __launch_bounds__(256) void fc_tail2_k(
    const float* __restrict__ h1,
    const float* __restrict__ fw2,  const float* __restrict__ fb2,
    const float* __restrict__ fw3,  const float* __restrict__ fb3,
    float* __restrict__ theta_out)
{
    __shared__ float hs[1024];
    __shared__ float h2s[32];
    const int m = blockIdx.x;
    const int tid = threadIdx.x;

    for (int i = tid; i < 1024; i += 256) hs[i] = h1[m * 1024 + i];
    __syncthreads();

    const int wave = tid >> 6, lane = tid & 63;
#pragma unroll 1
    for (int nn = 0; nn < 8; ++nn) {
        int n = wave * 8 + nn;
        float p = 0.0f;
        for (int k = lane; k < 1024; k += 64)
            p += fw2[n * 1024 + k] * hs[k];
#pragma unroll
        for (int off = 32; off; off >>= 1) p += __shfl_xor(p, off);
        if (lane == 0) h2s[n] = fmaxf(p + fb2[n], 0.0f);
    }
    __syncthreads();

    if (tid < 4) {
        int j = tid;
        float s = fb3[j];
#pragma unroll
        for (int k = 0; k < 32; ++k) s += h2s[k] * fw3[j * 32 + k];
        float* th = theta_out + m * 6;
        if (j == 0)      { th[0] = 1.0f / (1.0f + expf(-s)); th[1] = 0.0f; }
        else if (j == 1) { th[4] = 1.0f / (1.0f + expf(-s)); th[3] = 0.0f; }
        else if (j == 2) { th[2] = tanhf(s); }
        else             { th[5] = tanhf(s); }
    }
}

// ---------------------------------------------------------------------------
// Bilinear grid-sample, padding_mode='zeros', align_corners=False. C=1.
// ---------------------------------------------------------------------------
__global__ __launch_bounds__(256) void sampler_k(
    const float* __restrict__ im, const float* __restrict__ theta,
    float* __restrict__ out)
{
    int idx = blockIdx.x * 256 + threadIdx.x;
    int x = idx & 255;
    int y = (idx >> 8) & 255;
    int b = idx >> 16;
    const float* th = theta + b * 6;
    float xsn = (2.0f * x + 1.0f) * (1.0f / 256.0f) - 1.0f;
    float ysn = (2.0f * y + 1.0f) * (1.0f / 256.0f) - 1.0f;
    float gx = th[0] * xsn + th[1] * ysn + th[2];
    float gy = th[3] * xsn + th[4] * ysn + th[5];
    float ix = ((gx + 1.0f) * 256.0f - 1.0f) * 0.5f;
    float iy = ((gy + 1.0f) * 256.0f - 1.0f) * 0.5f;
    float x0 = floorf(ix), y0 = floorf(iy);
    float wx1 = ix - x0, wy1 = iy - y0;
    float wx0 = 1.0f - wx1, wy0 = 1.0f - wy1;
    const float* src = im + (size_t)b * 65536;

    auto g = [&](float xf, float yf) -> float {
        if (xf < 0.0f || xf > 255.0f || yf < 0.0f || yf > 255.0f) return 0.0f;
        int xi = (int)xf, yi = (int)yf;
        return src[yi * 256 + xi];
    };
    float v00 = g(x0, y0);
    float v10 = g(x0 + 1.0f, y0);
    float v01 = g(x0, y0 + 1.0f);
    float v11 = g(x0 + 1.0f, y0 + 1.0f);
    out[idx] = v00 * wx0 * wy0 + v10 * wx1 * wy0 + v01 * wx0 * wy1 + v11 * wx1 * wy1;
}

// ---------------------------------------------------------------------------
// Workspace layouts (floats):
// CHUNKED (ws < 84MB): x2@0, x1c@4194304, x3@4194304, x4@12582912,
//   x5@4194304, x6@14680064; part@0 (2,097,152), h1@2097152 (ends 2129920,
//   < x1c/x3 region — x2/x3 dead by then). Peak 61.9MB.
// BIG (ws >= 84MB): x2@0, x1@4194304 (ends 20971520), x3@4194304,
//   x4@12582912, x5@14680064, x6@17825792; part@0, h1@2097152.
// Grid formula everywhere: B * NG * tpc * tpr (audited per launch).
// ---------------------------------------------------------------------------
extern "C" void kernel_launch(void* const* d_in, const int* in_sizes, int n_in,
                              void* d_out, int out_size, void* d_ws, size_t ws_size,
                              hipStream_t stream)
{
    const float* im  = (const float*)d_in[0];
    const float* w1  = (const float*)d_in[1];  const float* b1 = (const float*)d_in[2];
    const float* w2  = (const float*)d_in[3];  const float* b2 = (const float*)d_in[4];
    const float* w3  = (const float*)d_in[5];  const float* b3 = (const float*)d_in[6];
    const float* w4  = (const float*)d_in[7];  const float* b4 = (const float*)d_in[8];
    const float* w5  = (const float*)d_in[9];  const float* b5 = (const float*)d_in[10];
    const float* w6  = (const float*)d_in[11]; const float* b6 = (const float*)d_in[12];
    const float* fw1 = (const float*)d_in[13]; const float* fb1 = (const float*)d_in[14];
    const float* fw2 = (const float*)d_in[15]; const float* fb2 = (const float*)d_in[16];
    const float* fw3 = (const float*)d_in[17]; const float* fb3 = (const float*)d_in[18];

    float* out = (float*)d_out;
    float* ws  = (float*)d_ws;

    float* theta = out + 32 * 65536;

    const bool big = ws_size >= (size_t)20971520 * 4;  // 83.9 MB

    float* x2   = ws + 0;
    float* part = ws + 0;
    float* h1   = ws + 2097152;

    if (big) {
        float* x1 = ws + 4194304;   // 32x8x256x256
        float* x3 = ws + 4194304;
        float* x4 = ws + 12582912;
        float* x5 = ws + 14680064;
        float* x6 = ws + 17825792;

        // conv1: B32 NG1 tpc8 tpr8 = 2048
        convq_k<1, 0, 8, 8, 1, 4><<<2048, 256, 0, stream>>>(
            im, nullptr, w1, b1, x1, 256, 256);
        // conv2: B32 NG1 tpc8 tpr4 = 1024
        conv2p_k<8, 1, 8, 8, 2, 1, 6><<<1024, 256, 0, stream>>>(
            x1, im, w2, b2, x2, 256, 256);
        // conv3: B32 NG2 tpc4 tpr4 = 1024
        convq_k<8, 0, 16, 8, 2, 4><<<1024, 256, 0, stream>>>(
            x2, nullptr, w3, b3, x3, 128, 128);
        // conv4: B32 NG2 tpc4 tpr2 = 512
        conv2p_k<16, 8, 16, 8, 2, 1, 6><<<512, 256, 0, stream>>>(
            x3, x2, w4, b4, x4, 128, 128);
        // conv5: B32 NG4 tpc2 tpr2 = 512
        convq_k<16, 0, 24, 6, 2, 4><<<512, 256, 0, stream>>>(
            x4, nullptr, w5, b5, x5, 64, 64);
        // conv6: B32 NG6 tpc2 tpr1 = 384
        conv2p_k<24, 16, 24, 4, 2, 1, 6><<<384, 256, 0, stream>>>(
            x5, x4, w6, b6, x6, 64, 64);

        fc1_stage_k<<<dim3(16, FC1_KS), 256, 0, stream>>>(x6, fw1, part);
        fc1_reduce_k<<<128, 256, 0, stream>>>(part, fb1, h1);
        fc_tail2_k<<<32, 256, 0, stream>>>(h1, fw2, fb2, fw3, fb3, theta);
    } else {
        float* x1c = ws + 4194304;  // 16-batch chunk
        float* x3  = ws + 4194304;
        float* x4  = ws + 12582912;
        float* x5  = ws + 4194304;
        float* x6  = ws + 14680064;

        for (int c = 0; c < 2; ++c) {
            const float* imc = im + (size_t)c * 16 * 65536;
            // conv1 chunk: B16 NG1 tpc8 tpr8 = 1024
            convq_k<1, 0, 8, 8, 1, 4><<<1024, 256, 0, stream>>>(
                imc, nullptr, w1, b1, x1c, 256, 256);
            // conv2 chunk: B16 NG1 tpc8 tpr4 = 512
            conv2p_k<8, 1, 8, 8, 2, 1, 6><<<512, 256, 0, stream>>>(
                x1c, imc, w2, b2, x2 + (size_t)c * 2097152, 256, 256);
        }
        // conv3: B32 NG2 tpc4 tpr4 = 1024
        convq_k<8, 0, 16, 8, 2, 4><<<1024, 256, 0, stream>>>(
            x2, nullptr, w3, b3, x3, 128, 128);
        // conv4: B32 NG2 tpc4 tpr2 = 512
        conv2p_k<16, 8, 16, 8, 2, 1, 6><<<512, 256, 0, stream>>>(
            x3, x2, w4, b4, x4, 128, 128);
        // conv5: B32 NG4 tpc2 tpr2 = 512
        convq_k<16, 0, 24, 6, 2, 4><<<512, 256, 0, stream>>>(
            x4, nullptr, w5, b5, x5, 64, 64);
        // conv6: B32 NG6 tpc2 tpr1 = 384
        conv2p_k<24, 16, 24, 4, 2, 1, 6><<<384, 256, 0, stream>>>(
            x5, x4, w6, b6, x6, 64, 64);

        fc1_stage_k<<<dim3(16, FC1_KS), 256, 0, stream>>>(x6, fw1, part);
        fc1_reduce_k<<<128, 256, 0, stream>>>(part, fb1, h1);
        fc_tail2_k<<<32, 256, 0, stream>>>(h1, fw2, fb2, fw3, fb3, theta);
    }

    // grid sample from theta (written into d_out tail, stream-ordered)
    sampler_k<<<8192, 256, 0, stream>>>(im, theta, out);
}